// Round 7
// baseline (218.809 us; speedup 1.0000x reference)
//
#include <hip/hip_runtime.h>

// DilatedAttention b=2,h=16,s=8192,d=64; W=[4,8,16], R=[1,2,4] -> L=4/group.
// 16-span self-contained. One wave per span via MFMA 16x16x32 bf16 (split
// hi/lo Q,K for ~fp32 QK^T; PV uses hi/lo P x RNE-hi V). R7: 2 spans per
// wave with cross-span register prefetch so global loads stay outstanding
// during compute (MLP fix for the ~2 TB/s latency cap seen in R2-R6).

#define S_SEQ 8192
#define D     64
#define NTHR  256

typedef __attribute__((ext_vector_type(8))) short bf16x8;
typedef __attribute__((ext_vector_type(4))) float f32x4;

union B8 { unsigned u[4]; bf16x8 v; };

// pack truncated-bf16 of (a,b) into dword (a->low), residuals out
static __device__ __forceinline__ unsigned pk_hi(float a, float b, float& ra, float& rb) {
    unsigned ua = __float_as_uint(a), ub = __float_as_uint(b);
    ra = a - __uint_as_float(ua & 0xFFFF0000u);
    rb = b - __uint_as_float(ub & 0xFFFF0000u);
    return (ua >> 16) | (ub & 0xFFFF0000u);
}
static __device__ __forceinline__ unsigned pk(float a, float b) {
    return (__float_as_uint(a) >> 16) | (__float_as_uint(b) & 0xFFFF0000u);
}
// round-to-nearest-even bf16 pack (for hi-only V)
static __device__ __forceinline__ unsigned pk_rne(float a, float b) {
    unsigned ua = __float_as_uint(a), ub = __float_as_uint(b);
    ua += 0x7FFFu + ((ua >> 16) & 1u);
    ub += 0x7FFFu + ((ub >> 16) & 1u);
    return (ua >> 16) | (ub & 0xFFFF0000u);
}

static __device__ __forceinline__ void mk_frag(const float* f, B8& hi, B8& lo) {
    float r[8];
#pragma unroll
    for (int i = 0; i < 4; ++i) hi.u[i] = pk_hi(f[2 * i], f[2 * i + 1], r[2 * i], r[2 * i + 1]);
#pragma unroll
    for (int i = 0; i < 4; ++i) lo.u[i] = pk(r[2 * i], r[2 * i + 1]);
}
static __device__ __forceinline__ void mk_hi(const float* f, B8& hi) {
#pragma unroll
    for (int i = 0; i < 4; ++i) hi.u[i] = pk_rne(f[2 * i], f[2 * i + 1]);
}

static __device__ __forceinline__ void load_qk(const float* q, const float* k,
                                               long long sp, int jc, int g,
                                               float4 qv[4], float4 kv[4]) {
    const float4* q4 = (const float4*)(q + sp * 1024);
    const float4* k4 = (const float4*)(k + sp * 1024);
#pragma unroll
    for (int c = 0; c < 2; ++c) {
        qv[2 * c]     = q4[jc * 16 + g * 2 + 8 * c];
        qv[2 * c + 1] = q4[jc * 16 + g * 2 + 8 * c + 1];
        kv[2 * c]     = k4[jc * 16 + g * 2 + 8 * c];
        kv[2 * c + 1] = k4[jc * 16 + g * 2 + 8 * c + 1];
    }
}

static __device__ __forceinline__ void load_v(const float* v, long long sp,
                                              int jc, int g, float vf[4][8]) {
    const float* vb = v + sp * 1024 + jc;
#pragma unroll
    for (int c = 0; c < 4; ++c)
#pragma unroll
        for (int jj = 0; jj < 8; ++jj)
            vf[c][jj] = vb[((g & 1) * 8 + jj) * 64 + 16 * c];
}

static __device__ __forceinline__ void compute_span(
    const float4 qv[4], const float4 kv[4], const float vf[4][8],
    float* __restrict__ out, long long sp, float* lpr, int jc, int g,
    float w0m, float jm1, float jm2) {
    // ---- QK^T: split-bf16 3-term ----
    B8 qh[2], ql[2], kh[2], kl[2];
#pragma unroll
    for (int c = 0; c < 2; ++c) {
        mk_frag((const float*)&qv[2 * c], qh[c], ql[c]);
        mk_frag((const float*)&kv[2 * c], kh[c], kl[c]);
    }
    f32x4 S = {0.f, 0.f, 0.f, 0.f};
    S = __builtin_amdgcn_mfma_f32_16x16x32_bf16(qh[0].v, kh[0].v, S, 0, 0, 0);
    S = __builtin_amdgcn_mfma_f32_16x16x32_bf16(qh[1].v, kh[1].v, S, 0, 0, 0);
    S = __builtin_amdgcn_mfma_f32_16x16x32_bf16(qh[0].v, kl[0].v, S, 0, 0, 0);
    S = __builtin_amdgcn_mfma_f32_16x16x32_bf16(qh[1].v, kl[1].v, S, 0, 0, 0);
    S = __builtin_amdgcn_mfma_f32_16x16x32_bf16(ql[0].v, kh[0].v, S, 0, 0, 0);
    S = __builtin_amdgcn_mfma_f32_16x16x32_bf16(ql[1].v, kh[1].v, S, 0, 0, 0);

    // ---- softmax per group on C layout (row i=g*4+r, col j=jc) ----
#pragma unroll
    for (int r = 0; r < 4; ++r) {
        float s = S[r] * 0.125f;
        float m0 = fmaxf(s, __shfl_xor(s, 1, 64));
        m0 = fmaxf(m0, __shfl_xor(m0, 2, 64));
        float e0 = __expf(s - m0);
        float t0 = e0 + __shfl_xor(e0, 1, 64);
        t0 += __shfl_xor(t0, 2, 64);
        float P = w0m * e0 / t0;
        if ((r & 1) == 0) {
            float m1 = fmaxf(s, __shfl_xor(s, 2, 64));
            m1 = fmaxf(m1, __shfl_xor(m1, 4, 64));
            float e1 = __expf(s - m1);
            float t1 = e1 + __shfl_xor(e1, 2, 64);
            t1 += __shfl_xor(t1, 4, 64);
            P += jm1 * e1 / t1;
        }
        if (r == 0) {
            float m2 = fmaxf(s, __shfl_xor(s, 4, 64));
            m2 = fmaxf(m2, __shfl_xor(m2, 8, 64));
            float e2 = __expf(s - m2);
            float t2 = e2 + __shfl_xor(e2, 4, 64);
            t2 += __shfl_xor(t2, 8, 64);
            P += jm2 * e2 / t2;
        }
        lpr[(g * 4 + r) * 20 + jc] = P;
    }

    // ---- P: C->A layout via LDS (same wave, in-order DS queue) ----
    float pf[8];
    *(float4*)&pf[0] = *(const float4*)&lpr[jc * 20 + (g & 1) * 8];
    *(float4*)&pf[4] = *(const float4*)&lpr[jc * 20 + (g & 1) * 8 + 4];
    B8 ph, pl2;
    mk_frag(pf, ph, pl2);
    if (g >= 2) {
#pragma unroll
        for (int i = 0; i < 4; ++i) { ph.u[i] = 0; pl2.u[i] = 0; }
    }

    // ---- PV: 2-term (hi/lo P x hi V), 4 d-chunks ----
    f32x4 acc[4];
#pragma unroll
    for (int c = 0; c < 4; ++c) {
        B8 vh;
        mk_hi(vf[c], vh);
        f32x4 a = {0.f, 0.f, 0.f, 0.f};
        a = __builtin_amdgcn_mfma_f32_16x16x32_bf16(ph.v,  vh.v, a, 0, 0, 0);
        a = __builtin_amdgcn_mfma_f32_16x16x32_bf16(pl2.v, vh.v, a, 0, 0, 0);
        acc[c] = a;
    }

    float* ob = out + sp * 1024 + jc;
#pragma unroll
    for (int c = 0; c < 4; ++c)
#pragma unroll
        for (int r = 0; r < 4; ++r)
            ob[(g * 4 + r) * 64 + 16 * c] = acc[c][r];
}

__global__ __launch_bounds__(NTHR, 4) void dilated_attn_kernel(
    const float* __restrict__ q, const float* __restrict__ k,
    const float* __restrict__ v, const float* __restrict__ alpha,
    float* __restrict__ out, int nwaves) {
    __shared__ float lp[4][16 * 20];

    const int l  = threadIdx.x & 63;
    const int wv = threadIdx.x >> 6;
    const int jc = l & 15;
    const int g  = l >> 4;
    const long long spA = blockIdx.x * 4 + wv;       // span 1
    const long long spB = spA + nwaves;              // span 2
    float* lpr = lp[wv];

    // ---- prefetch: A's Q/K + V, then B's Q/K (outstanding through compute A)
    float4 qA[4], kA[4], qB[4], kB[4];
    float vA[4][8];
    load_qk(q, k, spA, jc, g, qA, kA);
    load_v(v, spA, jc, g, vA);
    load_qk(q, k, spB, jc, g, qB, kB);

    // alpha softmax -> per-lane masked mixture weights
    float a0 = alpha[0], a1 = alpha[1], a2 = alpha[2];
    float am = fmaxf(a0, fmaxf(a1, a2));
    float e0a = __expf(a0 - am), e1a = __expf(a1 - am), e2a = __expf(a2 - am);
    float inv = 1.0f / (e0a + e1a + e2a);
    const float w0m = ((jc >> 2) == g) ? e0a * inv : 0.f;
    const float jm1 = (((jc & 1) == 0) && ((jc >> 3) == (g >> 1))) ? e1a * inv : 0.f;
    const float jm2 = (jc & 3) ? 0.f : e2a * inv;

    compute_span(qA, kA, vA, out, spA, lpr, jc, g, w0m, jm1, jm2);

    float vB[4][8];
    load_v(v, spB, jc, g, vB);

    compute_span(qB, kB, vB, out, spB, lpr, jc, g, w0m, jm1, jm2);
}

extern "C" void kernel_launch(void* const* d_in, const int* in_sizes, int n_in,
                              void* d_out, int out_size, void* d_ws, size_t ws_size,
                              hipStream_t stream) {
    const float* q = (const float*)d_in[0];
    const float* k = (const float*)d_in[1];
    const float* v = (const float*)d_in[2];
    const float* alpha = (const float*)d_in[3];
    float* out = (float*)d_out;

    const int BH = in_sizes[0] / (S_SEQ * D);          // 32
    const int tot_spans = BH * (S_SEQ / 16);           // 16384
    const int nwaves = tot_spans / 2;                  // 8192 (2 spans/wave)
    const int nblk = nwaves / 4;                       // 2048 blocks
    hipLaunchKernelGGL(dilated_attn_kernel, dim3(nblk), dim3(NTHR), 0,
                       stream, q, k, v, alpha, out, nwaves);
}